// Round 9
// baseline (603.229 us; speedup 1.0000x reference)
//
#include <hip/hip_runtime.h>
#include <cstdint>
#include <cstddef>

#define B_ 16
#define S_ 64
#define T_ 4096
#define C_ 512
#define H_ 8

// ws layout (float offsets):
#define WS_QKT     0         // [512][8]
#define WS_QB      4096      // [8]
#define WS_QH      4104      // [512]
#define WS_WSUM    552960    // [1024][8][512] (4194304)
#define WS_ATTNOUT 4747264   // [1024][512]    (524288)

// P1: qh[r] = (Wq@x + bq)[r] / 8.  grid 16, block 256 (32 rows/block).
__global__ void k_prep1(const float* __restrict__ x, const float* __restrict__ Wq,
                        const float* __restrict__ bq, float* __restrict__ qh_g) {
  __shared__ float xs[C_];
  __shared__ float red[256];
  int tid = threadIdx.x;
  xs[tid] = x[tid];
  xs[tid + 256] = x[tid + 256];
  __syncthreads();
  int r0 = blockIdx.x * 32;
  int rl = tid >> 3, sub = tid & 7;
  int r = r0 + rl;
  const float* wr = Wq + (size_t)r * C_ + sub * 64;
  const float* xp = xs + sub * 64;
  float s = 0.f;
#pragma unroll
  for (int i = 0; i < 64; i += 4) {
    float4 w = *(const float4*)(wr + i);
    s += w.x * xp[i] + w.y * xp[i + 1] + w.z * xp[i + 2] + w.w * xp[i + 3];
  }
  red[tid] = s;
  __syncthreads();
  if (sub == 0) {
    float tot = bq[r];
#pragma unroll
    for (int i = 0; i < 8; ++i) tot += red[rl * 8 + i];
    qh_g[r] = tot * 0.125f;
  }
}

// P2: qkT[c][h] = sum_d qh[h*64+d]*Wk[h*64+d][c]; qb[h] = sum_d qh*bk.
// grid 8 (h), block 256. Coalesced over c per d.
__global__ void k_prep2(const float* __restrict__ qh_g,
                        const float* __restrict__ Wk,
                        const float* __restrict__ bk, float* __restrict__ qkT,
                        float* __restrict__ qb) {
  __shared__ float qhs[64];
  int tid = threadIdx.x;
  int h = blockIdx.x;
  if (tid < 64) qhs[tid] = qh_g[h * 64 + tid];
  __syncthreads();
  int c0 = tid, c1 = tid + 256;
  float s0 = 0.f, s1 = 0.f;
#pragma unroll 8
  for (int d = 0; d < 64; ++d) {
    const float* row = Wk + (size_t)(h * 64 + d) * C_;
    float q = qhs[d];
    s0 += q * row[c0];
    s1 += q * row[c1];
  }
  qkT[c0 * 8 + h] = s0;
  qkT[c1 * 8 + h] = s1;
  if (tid < 64) {
    float w = qhs[tid] * bk[h * 64 + tid];
#pragma unroll
    for (int off = 32; off > 0; off >>= 1) w += __shfl_down(w, off, 64);
    if (tid == 0) qb[h] = w;
  }
}

// K_FUSED: one block per segment n. Online-softmax flash-style sweep over the
// segment in 64-t chunks:
//   phase A: att[h][tl] = qb[h] + sum_c qkT[c][h]*eh[b][c][t0+tl]
//            (k_att's proven 4x(128c)x64t structure, coalesced lane<->t)
//   phase B: chunk max -> m_new; f = exp(m_old-m_new); p = exp(att-m_new);
//            l = l*f + sum(p)   (masked outside [st,en))
//   phase C: accw[c][h] = accw[c][h]*f + sum_t p[h][t]*eh[b][c][t]
//            (R3's 4-lane-group quad loads, 16 lines/instr; eh window is
//            L2-hot from phase A ~2us earlier; accw lives in LDS)
// Epilogue: wsum[n][h][c] = accw[c][h] / l[h].
// Eliminates: att materialization, k_stats, chunk map, wsum zeroing, atomics.
__global__ __launch_bounds__(256, 3) void k_fused(
    const float* __restrict__ eh, const float* __restrict__ qkT,
    const float* __restrict__ qb_g, const int* __restrict__ starts,
    const int* __restrict__ ends, float* __restrict__ wsum) {
  __shared__ __attribute__((aligned(16))) float qks[C_ * 8];   // 16 KB
  __shared__ __attribute__((aligned(16))) float part[4 * 8 * 64];  // 8 KB
  __shared__ __attribute__((aligned(16))) float ps[8 * 72];    // 2.3 KB
  __shared__ __attribute__((aligned(16))) float accw[C_ * 8];  // 16 KB [c][h]
  __shared__ float qbs[8], mlds[8], llds[8], flds[8];
  int tid = threadIdx.x;
  int n = blockIdx.x;
  int b = n >> 6;
  int st = starts[n], en = ends[n];
  int base0 = st & ~15;
  int nch = (en - base0 + 63) >> 6;

#pragma unroll
  for (int i2 = 0; i2 < 16; ++i2) qks[tid + i2 * 256] = qkT[tid + i2 * 256];
#pragma unroll
  for (int i2 = 0; i2 < 16; ++i2) accw[tid + i2 * 256] = 0.f;
  if (tid < 8) {
    qbs[tid] = qb_g[tid];
    mlds[tid] = -3.0e38f;
    llds[tid] = 0.f;
  }
  __syncthreads();

  int tl = tid & 63, cg = tid >> 6;
  int il = tl & 3, g = tl >> 2, wv = cg;  // phase C mapping
  int hh = tid >> 5, l32 = tid & 31;      // phase B mapping

  for (int c = 0; c < nch; ++c) {
    int t0 = base0 + (c << 6);

    // ---- phase A: att for [t0, t0+64) ----
    {
      int tt = t0 + tl;
      if (tt > T_ - 1) tt = T_ - 1;  // address clamp; value masked below
      const float* ehp = eh + ((size_t)b * C_ + (size_t)cg * 128) * T_ + tt;
      float a0 = 0.f, a1 = 0.f, a2 = 0.f, a3 = 0.f;
      float a4 = 0.f, a5 = 0.f, a6 = 0.f, a7 = 0.f;
#pragma unroll 4
      for (int j = 0; j < 128; ++j) {
        float e = ehp[(size_t)j * T_];
        const float4 q0 = *(const float4*)&qks[(cg * 128 + j) * 8];
        const float4 q1 = *(const float4*)&qks[(cg * 128 + j) * 8 + 4];
        a0 += q0.x * e; a1 += q0.y * e; a2 += q0.z * e; a3 += q0.w * e;
        a4 += q1.x * e; a5 += q1.y * e; a6 += q1.z * e; a7 += q1.w * e;
      }
      part[(cg * 8 + 0) * 64 + tl] = a0;
      part[(cg * 8 + 1) * 64 + tl] = a1;
      part[(cg * 8 + 2) * 64 + tl] = a2;
      part[(cg * 8 + 3) * 64 + tl] = a3;
      part[(cg * 8 + 4) * 64 + tl] = a4;
      part[(cg * 8 + 5) * 64 + tl] = a5;
      part[(cg * 8 + 6) * 64 + tl] = a6;
      part[(cg * 8 + 7) * 64 + tl] = a7;
    }
    __syncthreads();
#pragma unroll
    for (int i2 = 0; i2 < 2; ++i2) {
      int idx = tid + i2 * 256;
      int h = idx >> 6, tt2 = idx & 63;
      int t = t0 + tt2;
      float v = part[(0 * 8 + h) * 64 + tt2] + part[(1 * 8 + h) * 64 + tt2] +
                part[(2 * 8 + h) * 64 + tt2] + part[(3 * 8 + h) * 64 + tt2] +
                qbs[h];
      ps[h * 72 + tt2] = (t >= st && t < en) ? v : -3.0e38f;
    }
    __syncthreads();

    // ---- phase B: online softmax update ----
    {
      float v0 = ps[hh * 72 + l32], v1 = ps[hh * 72 + 32 + l32];
      float cmax = fmaxf(v0, v1);
#pragma unroll
      for (int off = 16; off > 0; off >>= 1)
        cmax = fmaxf(cmax, __shfl_xor(cmax, off, 32));
      float mo = mlds[hh];
      float mn = fmaxf(mo, cmax);
      float f = __expf(mo - mn);
      float p0 = __expf(v0 - mn), p1 = __expf(v1 - mn);
      ps[hh * 72 + l32] = p0;
      ps[hh * 72 + 32 + l32] = p1;
      float cs = p0 + p1;
#pragma unroll
      for (int off = 16; off > 0; off >>= 1) cs += __shfl_xor(cs, off, 32);
      if (l32 == 0) {
        mlds[hh] = mn;
        llds[hh] = llds[hh] * f + cs;
        flds[hh] = f;
      }
    }
    __syncthreads();

    // ---- phase C: rescale accw, then accumulate chunk ----
    {
      float f0 = flds[0], f1 = flds[1], f2 = flds[2], f3 = flds[3];
      float f4 = flds[4], f5 = flds[5], f6 = flds[6], f7 = flds[7];
      int base4 = tid * 16;  // entries [c=2*tid, 2*tid+1] x h=0..7
      float4 w0 = *(float4*)&accw[base4 + 0];
      float4 w1 = *(float4*)&accw[base4 + 4];
      float4 w2 = *(float4*)&accw[base4 + 8];
      float4 w3 = *(float4*)&accw[base4 + 12];
      w0.x *= f0; w0.y *= f1; w0.z *= f2; w0.w *= f3;
      w1.x *= f4; w1.y *= f5; w1.z *= f6; w1.w *= f7;
      w2.x *= f0; w2.y *= f1; w2.z *= f2; w2.w *= f3;
      w3.x *= f4; w3.y *= f5; w3.z *= f6; w3.w *= f7;
      *(float4*)&accw[base4 + 0] = w0;
      *(float4*)&accw[base4 + 4] = w1;
      *(float4*)&accw[base4 + 8] = w2;
      *(float4*)&accw[base4 + 12] = w3;
    }
    __syncthreads();
#pragma unroll
    for (int pass = 0; pass < 8; ++pass) {
      int ch = pass * 64 + wv * 16 + g;
      const float* erow = eh + ((size_t)b * C_ + ch) * T_;
      float a0 = 0.f, a1 = 0.f, a2 = 0.f, a3 = 0.f;
      float a4 = 0.f, a5 = 0.f, a6 = 0.f, a7 = 0.f;
#pragma unroll
      for (int kk = 0; kk < 4; ++kk) {
        int j0 = (kk << 4) | (il << 2);
        int tg = t0 + j0;
        if (tg > T_ - 4) tg = T_ - 4;  // quad-aligned clamp; p there is 0
        float4 ev = *(const float4*)(erow + tg);
        const float* pp = ps + j0;
        float4 p;
        p = *(const float4*)(pp + 0 * 72);
        a0 += p.x * ev.x + p.y * ev.y + p.z * ev.z + p.w * ev.w;
        p = *(const float4*)(pp + 1 * 72);
        a1 += p.x * ev.x + p.y * ev.y + p.z * ev.z + p.w * ev.w;
        p = *(const float4*)(pp + 2 * 72);
        a2 += p.x * ev.x + p.y * ev.y + p.z * ev.z + p.w * ev.w;
        p = *(const float4*)(pp + 3 * 72);
        a3 += p.x * ev.x + p.y * ev.y + p.z * ev.z + p.w * ev.w;
        p = *(const float4*)(pp + 4 * 72);
        a4 += p.x * ev.x + p.y * ev.y + p.z * ev.z + p.w * ev.w;
        p = *(const float4*)(pp + 5 * 72);
        a5 += p.x * ev.x + p.y * ev.y + p.z * ev.z + p.w * ev.w;
        p = *(const float4*)(pp + 6 * 72);
        a6 += p.x * ev.x + p.y * ev.y + p.z * ev.z + p.w * ev.w;
        p = *(const float4*)(pp + 7 * 72);
        a7 += p.x * ev.x + p.y * ev.y + p.z * ev.z + p.w * ev.w;
      }
      a0 += __shfl_xor(a0, 1); a0 += __shfl_xor(a0, 2);
      a1 += __shfl_xor(a1, 1); a1 += __shfl_xor(a1, 2);
      a2 += __shfl_xor(a2, 1); a2 += __shfl_xor(a2, 2);
      a3 += __shfl_xor(a3, 1); a3 += __shfl_xor(a3, 2);
      a4 += __shfl_xor(a4, 1); a4 += __shfl_xor(a4, 2);
      a5 += __shfl_xor(a5, 1); a5 += __shfl_xor(a5, 2);
      a6 += __shfl_xor(a6, 1); a6 += __shfl_xor(a6, 2);
      a7 += __shfl_xor(a7, 1); a7 += __shfl_xor(a7, 2);
      float s0 = (il < 2) ? ((il == 0) ? a0 : a2) : ((il == 2) ? a4 : a6);
      float s1 = (il < 2) ? ((il == 0) ? a1 : a3) : ((il == 2) ? a5 : a7);
      int h0 = il << 1;
      accw[ch * 8 + h0] += s0;
      accw[ch * 8 + h0 + 1] += s1;
    }
    __syncthreads();
  }

  // ---- epilogue: wsum[n][h][c] = accw[c][h] / l[h] ----
  float* wp = wsum + (size_t)n * (H_ * C_);
#pragma unroll
  for (int h = 0; h < 8; ++h) {
    float inv = 1.f / llds[h];
    wp[h * C_ + tid] = accw[tid * 8 + h] * inv;
    wp[h * C_ + 256 + tid] = accw[(256 + tid) * 8 + h] * inv;
  }
}

// K6/K7: C[n][y*64+j] = sum_k A[n*aRow + y*aColPerY + k]*Bm[(y*64+j)*512+k]
//        + bias[y*64+j].  32x64 tile, 256 threads, 2x4 per thread (R2 form).
__global__ __launch_bounds__(256, 4) void k_gemm(
    const float* __restrict__ A, long aRow, long aColPerY,
    const float* __restrict__ Bm, const float* __restrict__ bias,
    float* __restrict__ Cc) {
  __shared__ float As[32 * 36];
  __shared__ float Bs[64 * 36];
  int tid = threadIdx.x;
  int n0 = blockIdx.x * 32;
  int y = blockIdx.y;
  const float* Abase = A + (size_t)n0 * aRow + (size_t)y * aColPerY;
  const float* Bbase = Bm + (size_t)(y * 64) * C_;
  int tx = tid & 15, ty = tid >> 4;
  float acc[2][4];
#pragma unroll
  for (int a = 0; a < 2; ++a)
#pragma unroll
    for (int bb = 0; bb < 4; ++bb) acc[a][bb] = 0.f;
  for (int k0 = 0; k0 < 512; k0 += 32) {
#pragma unroll
    for (int i = 0; i < 4; ++i) {
      int idx = tid + i * 256;
      int r = idx >> 5, cc = idx & 31;
      As[r * 36 + cc] = Abase[(size_t)r * aRow + k0 + cc];
    }
#pragma unroll
    for (int i = 0; i < 8; ++i) {
      int idx = tid + i * 256;
      int r = idx >> 5, cc = idx & 31;
      Bs[r * 36 + cc] = Bbase[(size_t)r * C_ + k0 + cc];
    }
    __syncthreads();
#pragma unroll
    for (int k = 0; k < 32; k += 4) {
      const float4 a0 = *(const float4*)&As[(ty * 2 + 0) * 36 + k];
      const float4 a1 = *(const float4*)&As[(ty * 2 + 1) * 36 + k];
#pragma unroll
      for (int bb = 0; bb < 4; ++bb) {
        const float4 bv = *(const float4*)&Bs[(tx * 4 + bb) * 36 + k];
        acc[0][bb] += a0.x * bv.x + a0.y * bv.y + a0.z * bv.z + a0.w * bv.w;
        acc[1][bb] += a1.x * bv.x + a1.y * bv.y + a1.z * bv.z + a1.w * bv.w;
      }
    }
    __syncthreads();
  }
#pragma unroll
  for (int a = 0; a < 2; ++a) {
    int nn = n0 + ty * 2 + a;
    float4 o;
    o.x = acc[a][0] + bias[y * 64 + tx * 4 + 0];
    o.y = acc[a][1] + bias[y * 64 + tx * 4 + 1];
    o.z = acc[a][2] + bias[y * 64 + tx * 4 + 2];
    o.w = acc[a][3] + bias[y * 64 + tx * 4 + 3];
    *(float4*)&Cc[(size_t)nn * C_ + y * 64 + tx * 4] = o;
  }
}

extern "C" void kernel_launch(void* const* d_in, const int* in_sizes, int n_in,
                              void* d_out, int out_size, void* d_ws,
                              size_t ws_size, hipStream_t stream) {
  const float* x = (const float*)d_in[0];
  const float* eh = (const float*)d_in[1];
  const int* shot_starts = (const int*)d_in[2];
  const int* shot_ends = (const int*)d_in[3];
  const float* Wq = (const float*)d_in[4];
  const float* bq = (const float*)d_in[5];
  const float* Wk = (const float*)d_in[6];
  const float* bk = (const float*)d_in[7];
  const float* Wv = (const float*)d_in[8];
  const float* bv = (const float*)d_in[9];
  const float* Wp = (const float*)d_in[10];
  const float* bp = (const float*)d_in[11];
  float* out = (float*)d_out;

  float* ws = (float*)d_ws;
  float* qkT = ws + WS_QKT;
  float* qb = ws + WS_QB;
  float* qh = ws + WS_QH;
  float* wsum = ws + WS_WSUM;
  float* attnout = ws + WS_ATTNOUT;

  k_prep1<<<16, 256, 0, stream>>>(x, Wq, bq, qh);
  k_prep2<<<8, 256, 0, stream>>>(qh, Wk, bk, qkT, qb);
  k_fused<<<B_ * S_, 256, 0, stream>>>(eh, qkT, qb, shot_starts, shot_ends,
                                       wsum);
  k_gemm<<<dim3(32, 8), 256, 0, stream>>>(wsum, (long)(H_ * C_), (long)C_, Wv,
                                          bv, attnout);
  k_gemm<<<dim3(32, 8), 256, 0, stream>>>(attnout, (long)C_, 0L, Wp, bp, out);
}

// Round 10
// 339.042 us; speedup vs baseline: 1.7792x; 1.7792x over previous
//
#include <hip/hip_runtime.h>
#include <cstdint>
#include <cstddef>

#define B_ 16
#define S_ 64
#define T_ 4096
#define C_ 512
#define H_ 8

// ws layout (float offsets):
#define WS_QKT     0         // [512][8]
#define WS_QB      4096      // [8]
#define WS_QH      4104      // [512]
#define WS_MS      4616      // [1024][8]
#define WS_LI      12808     // [1024][8]
#define WS_CNT     21000     // [16] int (only [0] used: total chunk count)
#define WS_CSEG    21016     // [2048] int (flat chunk -> segment n)
#define WS_CIDX    23064     // [2048] int (flat chunk -> chunk index k)
#define WS_CMUL    25112     // [2048] int (flat chunk -> multi-chunk flag)
#define WS_ATT     28672     // [B][H][T]      (524288)
#define WS_WSUM    552960    // [1024][8][512] (4194304)
#define WS_ATTNOUT 4747264   // [1024][512]    (524288)
// end 5271552 floats ~= 20.1 MB

// P1: qh[r] = (Wq@x + bq)[r] / 8.  grid 17, block 256 (32 rows/block).
// Block 16 instead builds the deterministic n-ordered chunk map (the old
// k_map): 256-thread scan, 4 segments/thread.
__global__ void k_prep1(const float* __restrict__ x, const float* __restrict__ Wq,
                        const float* __restrict__ bq, float* __restrict__ qh_g,
                        const int* __restrict__ starts,
                        const int* __restrict__ ends, int* __restrict__ cnt,
                        int* __restrict__ cseg, int* __restrict__ cidx,
                        int* __restrict__ cmul) {
  __shared__ float xs[C_];
  __shared__ float red[256];
  __shared__ int sc2[256];
  int tid = threadIdx.x;
  if (blockIdx.x == 16) {
    int n0 = tid * 4;
    int st0 = starts[n0 + 0], en0 = ends[n0 + 0];
    int st1 = starts[n0 + 1], en1 = ends[n0 + 1];
    int st2 = starts[n0 + 2], en2 = ends[n0 + 2];
    int st3 = starts[n0 + 3], en3 = ends[n0 + 3];
    int c0 = (en0 - (st0 & ~15) + 127) >> 7;
    int c1 = (en1 - (st1 & ~15) + 127) >> 7;
    int c2 = (en2 - (st2 & ~15) + 127) >> 7;
    int c3 = (en3 - (st3 & ~15) + 127) >> 7;
    int loc = c0 + c1 + c2 + c3;
    sc2[tid] = loc;
    __syncthreads();
    for (int off = 1; off < 256; off <<= 1) {
      int v = (tid >= off) ? sc2[tid - off] : 0;
      __syncthreads();
      sc2[tid] += v;
      __syncthreads();
    }
    int pre = sc2[tid] - loc;
#define EMIT(cX, nX)                                                  \
    {                                                                 \
      int m = (cX > 1) ? 1 : 0;                                       \
      for (int k = 0; k < cX; ++k) {                                  \
        cseg[pre + k] = nX; cidx[pre + k] = k; cmul[pre + k] = m;     \
      }                                                               \
      pre += cX;                                                      \
    }
    EMIT(c0, n0 + 0)
    EMIT(c1, n0 + 1)
    EMIT(c2, n0 + 2)
    EMIT(c3, n0 + 3)
#undef EMIT
    if (tid == 255) cnt[0] = sc2[255];
    return;
  }
  xs[tid] = x[tid];
  xs[tid + 256] = x[tid + 256];
  __syncthreads();
  int r0 = blockIdx.x * 32;
  int rl = tid >> 3, sub = tid & 7;
  int r = r0 + rl;
  const float* wr = Wq + (size_t)r * C_ + sub * 64;
  const float* xp = xs + sub * 64;
  float s = 0.f;
#pragma unroll
  for (int i = 0; i < 64; i += 4) {
    float4 w = *(const float4*)(wr + i);
    s += w.x * xp[i] + w.y * xp[i + 1] + w.z * xp[i + 2] + w.w * xp[i + 3];
  }
  red[tid] = s;
  __syncthreads();
  if (sub == 0) {
    float tot = bq[r];
#pragma unroll
    for (int i = 0; i < 8; ++i) tot += red[rl * 8 + i];
    qh_g[r] = tot * 0.125f;
  }
}

// P2: qkT[c][h] = sum_d qh[h*64+d]*Wk[h*64+d][c]; qb[h] = sum_d qh*bk.
// grid 8 (h), block 256. Coalesced over c per d.
__global__ void k_prep2(const float* __restrict__ qh_g,
                        const float* __restrict__ Wk,
                        const float* __restrict__ bk, float* __restrict__ qkT,
                        float* __restrict__ qb) {
  __shared__ float qhs[64];
  int tid = threadIdx.x;
  int h = blockIdx.x;
  if (tid < 64) qhs[tid] = qh_g[h * 64 + tid];
  __syncthreads();
  int c0 = tid, c1 = tid + 256;
  float s0 = 0.f, s1 = 0.f;
#pragma unroll 8
  for (int d = 0; d < 64; ++d) {
    const float* row = Wk + (size_t)(h * 64 + d) * C_;
    float q = qhs[d];
    s0 += q * row[c0];
    s1 += q * row[c1];
  }
  qkT[c0 * 8 + h] = s0;
  qkT[c1 * 8 + h] = s1;
  if (tid < 64) {
    float w = qhs[tid] * bk[h * 64 + tid];
#pragma unroll
    for (int off = 32; off > 0; off >>= 1) w += __shfl_down(w, off, 64);
    if (tid == 0) qb[h] = w;
  }
}

// K2: att[b][h][t] = qb[h] + sum_c qkT[c][h]*eh[b][c][t]
// grid (16, 16), block 256: 256 t per block (float4 per lane), 4 c-slices
// of 128. Same j-order accumulation as the scalar form => bit-identical.
__global__ __launch_bounds__(256, 4) void k_att(
    const float* __restrict__ eh, const float* __restrict__ qkT,
    const float* __restrict__ qb, float* __restrict__ att) {
  __shared__ float qks[C_ * 8];        // 16 KB
  __shared__ float part[4 * 8 * 256];  // 32 KB [cg][h][tt]
  int tid = threadIdx.x;
  int tl = tid & 63, cg = tid >> 6;
  int b = blockIdx.y;
  int t0 = blockIdx.x * 256;
#pragma unroll
  for (int i = 0; i < 16; ++i) qks[tid + i * 256] = qkT[tid + i * 256];
  __syncthreads();
  const float* ehp =
      eh + ((size_t)b * C_ + (size_t)cg * 128) * T_ + t0 + tl * 4;
  float4 acc[8];
#pragma unroll
  for (int h = 0; h < 8; ++h) acc[h] = make_float4(0.f, 0.f, 0.f, 0.f);
#define FMA4(A, s)                                                       \
  A.x += (s)*ev.x; A.y += (s)*ev.y; A.z += (s)*ev.z; A.w += (s)*ev.w;
#pragma unroll 4
  for (int j = 0; j < 128; ++j) {
    float4 ev = *(const float4*)&ehp[(size_t)j * T_];
    const float4 q0 = *(const float4*)&qks[(cg * 128 + j) * 8];
    const float4 q1 = *(const float4*)&qks[(cg * 128 + j) * 8 + 4];
    FMA4(acc[0], q0.x) FMA4(acc[1], q0.y) FMA4(acc[2], q0.z) FMA4(acc[3], q0.w)
    FMA4(acc[4], q1.x) FMA4(acc[5], q1.y) FMA4(acc[6], q1.z) FMA4(acc[7], q1.w)
  }
#undef FMA4
#pragma unroll
  for (int h = 0; h < 8; ++h)
    *(float4*)&part[(cg * 8 + h) * 256 + tl * 4] = acc[h];
  __syncthreads();
#pragma unroll
  for (int i = 0; i < 8; ++i) {
    int idx = tid + i * 256;
    int h = idx >> 8, tt = idx & 255;
    float v = part[(0 * 8 + h) * 256 + tt] + part[(1 * 8 + h) * 256 + tt] +
              part[(2 * 8 + h) * 256 + tt] + part[(3 * 8 + h) * 256 + tt] +
              qb[h];
    att[((size_t)b * H_ + h) * T_ + t0 + tt] = v;
  }
}

// K3: softmax stats per (n, h): ms = max, li = 1/sum(exp). grid 1024.
// Also zeroes wsum rows of multi-chunk segments (replaces the 16 MB
// memset; single-chunk rows are fully overwritten by k_wsum's stores).
__global__ void k_stats(const float* __restrict__ att,
                        const int* __restrict__ starts,
                        const int* __restrict__ ends, float* __restrict__ ms,
                        float* __restrict__ li, float* __restrict__ wsum) {
  int tid = threadIdx.x;
  int n = blockIdx.x;
  int b = n >> 6;
  int start = starts[n], end = ends[n];
  int nch = (end - (start & ~15) + 127) >> 7;
  if (nch > 1) {
    float4 z = make_float4(0.f, 0.f, 0.f, 0.f);
    float* wrow = wsum + (size_t)n * (H_ * C_);
#pragma unroll
    for (int i2 = 0; i2 < 4; ++i2) *(float4*)&wrow[(tid + i2 * 256) * 4] = z;
  }
  int h = tid >> 5, tl = tid & 31;
  const float* ah = att + ((size_t)b * H_ + h) * T_;
  float mloc = -3.0e38f;
  for (int t = start + tl; t < end; t += 32) mloc = fmaxf(mloc, ah[t]);
#pragma unroll
  for (int off = 16; off > 0; off >>= 1)
    mloc = fmaxf(mloc, __shfl_xor(mloc, off, 32));
  float lloc = 0.f;
  for (int t = start + tl; t < end; t += 32) lloc += __expf(ah[t] - mloc);
#pragma unroll
  for (int off = 16; off > 0; off >>= 1) lloc += __shfl_xor(lloc, off, 32);
  if (tl == 0) { ms[n * 8 + h] = mloc; li[n * 8 + h] = 1.f / lloc; }
}

// K5: wsum[n][h][c] = sum_{t in seg} p[h][t]*eh[b][c][t], one block per
// <=128-t chunk (flat, deterministic n-ordered list). Lane mapping: group
// g = lane>>2 owns channel (pass*64 + wave*16 + g); the 4 lanes il=0..3 of
// a group read one aligned 64B quad-row per k step => 16 cache lines per
// instruction. E consumed straight from registers; only p[] lives in LDS
// (broadcast reads). acc = 8 named scalars; t-reduction = 2 shfl_xor
// rounds per head. (R5 form — best measured; CPT=4/predication/swizzle/
// occupancy-8 all tested neutral-or-worse in R6-R8.)
__global__ __launch_bounds__(256, 4) void k_wsum(
    const float* __restrict__ eh, const float* __restrict__ att,
    const float* __restrict__ ms, const float* __restrict__ li,
    const int* __restrict__ starts, const int* __restrict__ ends,
    const int* __restrict__ cnt, const int* __restrict__ cseg,
    const int* __restrict__ cidx, const int* __restrict__ cmul,
    float* __restrict__ wsum) {
  __shared__ float pl[8 * 136];  // p[h][t-base], zero outside [t_lo, t_hi)
  int i = blockIdx.x;
  if (i >= cnt[0]) return;
  int tid = threadIdx.x;
  int n = cseg[i];
  int k = cidx[i];
  int mul = cmul[i];
  int b = n >> 6;
  int st = starts[n], en = ends[n];
  int cbase = st & ~15;
  int base = cbase + (k << 7);      // 16-float (64B) aligned
  int t_lo = (st > base) ? st : base;
  int t_hi = base + 128;
  if (en < t_hi) t_hi = en;
  int jmax = t_hi - base;           // 1..128
  int kmax = (jmax + 15) >> 4;      // 1..8 quad-row steps

  // stage p[h][t-base]
  {
    int h = tid >> 5, l32 = tid & 31;
    float msn = ms[n * 8 + h], lin = li[n * 8 + h];
    const float* ah = att + ((size_t)b * H_ + h) * T_;
    for (int j = l32; j < 136; j += 32) {
      int t = base + j;
      float pv = 0.f;
      if (t >= t_lo && t < t_hi) pv = __expf(ah[t] - msn) * lin;
      pl[h * 136 + j] = pv;
    }
  }
  __syncthreads();

  int l = tid & 63, wv = tid >> 6;
  int il = l & 3, g = l >> 2;  // 16 groups/wave; group owns one channel/pass
  float* wp = wsum + (size_t)n * (H_ * C_);

  for (int pass = 0; pass < 8; ++pass) {
    int ch = pass * 64 + wv * 16 + g;
    const float* erow = eh + ((size_t)b * C_ + ch) * T_;
    float a0 = 0.f, a1 = 0.f, a2 = 0.f, a3 = 0.f;
    float a4 = 0.f, a5 = 0.f, a6 = 0.f, a7 = 0.f;
#pragma unroll 2
    for (int kk = 0; kk < kmax; ++kk) {
      int j0 = (kk << 4) | (il << 2);
      int tg = base + j0;
      if (tg > T_ - 4) tg = T_ - 4;  // clamped quads multiply pl zeros
      float4 ev = *(const float4*)(erow + tg);
      const float* pp = pl + j0;
      float4 p;
      p = *(const float4*)(pp + 0 * 136);
      a0 += p.x * ev.x + p.y * ev.y + p.z * ev.z + p.w * ev.w;
      p = *(const float4*)(pp + 1 * 136);
      a1 += p.x * ev.x + p.y * ev.y + p.z * ev.z + p.w * ev.w;
      p = *(const float4*)(pp + 2 * 136);
      a2 += p.x * ev.x + p.y * ev.y + p.z * ev.z + p.w * ev.w;
      p = *(const float4*)(pp + 3 * 136);
      a3 += p.x * ev.x + p.y * ev.y + p.z * ev.z + p.w * ev.w;
      p = *(const float4*)(pp + 4 * 136);
      a4 += p.x * ev.x + p.y * ev.y + p.z * ev.z + p.w * ev.w;
      p = *(const float4*)(pp + 5 * 136);
      a5 += p.x * ev.x + p.y * ev.y + p.z * ev.z + p.w * ev.w;
      p = *(const float4*)(pp + 6 * 136);
      a6 += p.x * ev.x + p.y * ev.y + p.z * ev.z + p.w * ev.w;
      p = *(const float4*)(pp + 7 * 136);
      a7 += p.x * ev.x + p.y * ev.y + p.z * ev.z + p.w * ev.w;
    }
    // reduce each head over the 4 il lanes (butterfly; all lanes get totals)
    a0 += __shfl_xor(a0, 1); a0 += __shfl_xor(a0, 2);
    a1 += __shfl_xor(a1, 1); a1 += __shfl_xor(a1, 2);
    a2 += __shfl_xor(a2, 1); a2 += __shfl_xor(a2, 2);
    a3 += __shfl_xor(a3, 1); a3 += __shfl_xor(a3, 2);
    a4 += __shfl_xor(a4, 1); a4 += __shfl_xor(a4, 2);
    a5 += __shfl_xor(a5, 1); a5 += __shfl_xor(a5, 2);
    a6 += __shfl_xor(a6, 1); a6 += __shfl_xor(a6, 2);
    a7 += __shfl_xor(a7, 1); a7 += __shfl_xor(a7, 2);
    // lane il stores heads 2*il, 2*il+1
    float s0 = (il < 2) ? ((il == 0) ? a0 : a2) : ((il == 2) ? a4 : a6);
    float s1 = (il < 2) ? ((il == 0) ? a1 : a3) : ((il == 2) ? a5 : a7);
    int h0 = il << 1;
    if (!mul) {
      wp[h0 * C_ + ch] = s0;
      wp[(h0 + 1) * C_ + ch] = s1;
    } else {
      atomicAdd(&wp[h0 * C_ + ch], s0);
      atomicAdd(&wp[(h0 + 1) * C_ + ch], s1);
    }
  }
}

// K6/K7: C[n][y*64+j] = sum_k A[n*aRow + y*aColPerY + k]*Bm[(y*64+j)*512+k]
//        + bias[y*64+j].  32x64 tile, 256 threads, 2x4 per thread (R2 form).
__global__ __launch_bounds__(256, 4) void k_gemm(
    const float* __restrict__ A, long aRow, long aColPerY,
    const float* __restrict__ Bm, const float* __restrict__ bias,
    float* __restrict__ Cc) {
  __shared__ float As[32 * 36];
  __shared__ float Bs[64 * 36];
  int tid = threadIdx.x;
  int n0 = blockIdx.x * 32;
  int y = blockIdx.y;
  const float* Abase = A + (size_t)n0 * aRow + (size_t)y * aColPerY;
  const float* Bbase = Bm + (size_t)(y * 64) * C_;
  int tx = tid & 15, ty = tid >> 4;
  float acc[2][4];
#pragma unroll
  for (int a = 0; a < 2; ++a)
#pragma unroll
    for (int bb = 0; bb < 4; ++bb) acc[a][bb] = 0.f;
  for (int k0 = 0; k0 < 512; k0 += 32) {
#pragma unroll
    for (int i = 0; i < 4; ++i) {
      int idx = tid + i * 256;
      int r = idx >> 5, cc = idx & 31;
      As[r * 36 + cc] = Abase[(size_t)r * aRow + k0 + cc];
    }
#pragma unroll
    for (int i = 0; i < 8; ++i) {
      int idx = tid + i * 256;
      int r = idx >> 5, cc = idx & 31;
      Bs[r * 36 + cc] = Bbase[(size_t)r * C_ + k0 + cc];
    }
    __syncthreads();
#pragma unroll
    for (int k = 0; k < 32; k += 4) {
      const float4 a0 = *(const float4*)&As[(ty * 2 + 0) * 36 + k];
      const float4 a1 = *(const float4*)&As[(ty * 2 + 1) * 36 + k];
#pragma unroll
      for (int bb = 0; bb < 4; ++bb) {
        const float4 bv = *(const float4*)&Bs[(tx * 4 + bb) * 36 + k];
        acc[0][bb] += a0.x * bv.x + a0.y * bv.y + a0.z * bv.z + a0.w * bv.w;
        acc[1][bb] += a1.x * bv.x + a1.y * bv.y + a1.z * bv.z + a1.w * bv.w;
      }
    }
    __syncthreads();
  }
#pragma unroll
  for (int a = 0; a < 2; ++a) {
    int nn = n0 + ty * 2 + a;
    float4 o;
    o.x = acc[a][0] + bias[y * 64 + tx * 4 + 0];
    o.y = acc[a][1] + bias[y * 64 + tx * 4 + 1];
    o.z = acc[a][2] + bias[y * 64 + tx * 4 + 2];
    o.w = acc[a][3] + bias[y * 64 + tx * 4 + 3];
    *(float4*)&Cc[(size_t)nn * C_ + y * 64 + tx * 4] = o;
  }
}

extern "C" void kernel_launch(void* const* d_in, const int* in_sizes, int n_in,
                              void* d_out, int out_size, void* d_ws,
                              size_t ws_size, hipStream_t stream) {
  const float* x = (const float*)d_in[0];
  const float* eh = (const float*)d_in[1];
  const int* shot_starts = (const int*)d_in[2];
  const int* shot_ends = (const int*)d_in[3];
  const float* Wq = (const float*)d_in[4];
  const float* bq = (const float*)d_in[5];
  const float* Wk = (const float*)d_in[6];
  const float* bk = (const float*)d_in[7];
  const float* Wv = (const float*)d_in[8];
  const float* bv = (const float*)d_in[9];
  const float* Wp = (const float*)d_in[10];
  const float* bp = (const float*)d_in[11];
  float* out = (float*)d_out;

  float* ws = (float*)d_ws;
  float* qkT = ws + WS_QKT;
  float* qb = ws + WS_QB;
  float* qh = ws + WS_QH;
  float* ms = ws + WS_MS;
  float* li = ws + WS_LI;
  int* cnt = (int*)(ws + WS_CNT);
  int* cseg = (int*)(ws + WS_CSEG);
  int* cidx = (int*)(ws + WS_CIDX);
  int* cmul = (int*)(ws + WS_CMUL);
  float* att = ws + WS_ATT;
  float* wsum = ws + WS_WSUM;
  float* attnout = ws + WS_ATTNOUT;

  k_prep1<<<17, 256, 0, stream>>>(x, Wq, bq, qh, shot_starts, shot_ends, cnt,
                                  cseg, cidx, cmul);
  k_prep2<<<8, 256, 0, stream>>>(qh, Wk, bk, qkT, qb);
  k_att<<<dim3(T_ / 256, B_), 256, 0, stream>>>(eh, qkT, qb, att);
  k_stats<<<B_ * S_, 256, 0, stream>>>(att, shot_starts, shot_ends, ms, li,
                                       wsum);
  k_wsum<<<2048, 256, 0, stream>>>(eh, att, ms, li, shot_starts, shot_ends,
                                   cnt, cseg, cidx, cmul, wsum);
  k_gemm<<<dim3(32, 8), 256, 0, stream>>>(wsum, (long)(H_ * C_), (long)C_, Wv,
                                          bv, attnout);
  k_gemm<<<dim3(32, 8), 256, 0, stream>>>(attnout, (long)C_, 0L, Wp, bp, out);
}